// Round 2
// baseline (3290.972 us; speedup 1.0000x reference)
//
#include <hip/hip_runtime.h>
#include <hip/hip_bf16.h>
#include <math.h>

#define B_ 8
#define N_ 8192
#define C_ 64
#define M_ 2048
#define K_ 32
#define OUT_ 128
#define CIN_ 67
#define HID_ 268
#define EPS_ 1e-6f

typedef short short8 __attribute__((ext_vector_type(8)));
typedef float floatx4 __attribute__((ext_vector_type(4)));

__device__ __forceinline__ unsigned short f2bf(float f) {
  unsigned u = __builtin_bit_cast(unsigned, f);
  u += 0x7fffu + ((u >> 16) & 1u);   // RNE (MFMA input casts only)
  return (unsigned short)(u >> 16);
}
__device__ __forceinline__ float bf2f(unsigned short h) {
  return __builtin_bit_cast(float, (unsigned)h << 16);
}

// Reference-matching distance (verified r13, bit-exact): square fused into the
// 3-element reduce as FMA, index-ascending.
__device__ __forceinline__ float d2fma(float ax, float ay, float az,
                                       float bx, float by, float bz) {
#pragma clang fp contract(off)
  float dx = ax - bx, dy = ay - by, dz = az - bz;
  return __builtin_fmaf(dz, dz, __builtin_fmaf(dy, dy, dx * dx));
}

__device__ __forceinline__ float gelu_tanh(float v) {
  const float k0 = 0.7978845608028654f;  // sqrt(2/pi)
  const float k1 = 0.044715f;
  float u = k0 * (v + k1 * v * v * v);
  return 0.5f * v * (1.0f + tanhf(u));
}

// Morton spread of a 4-bit value to bit positions 0,3,6,9
__device__ __forceinline__ int msp4(int v) {
  return (v & 1) | ((v & 2) << 2) | ((v & 4) << 4) | ((v & 8) << 6);
}

// One DPP max step on a u64 key (VALU-only; keys are unsigned so the
// bound_ctrl zero-fill is the identity for max).
template <int CTRL>
__device__ __forceinline__ unsigned long long dpp_umax64(unsigned long long k) {
  int lo = (int)(unsigned)k;
  int hi = (int)(unsigned)(k >> 32);
  unsigned slo = (unsigned)__builtin_amdgcn_update_dpp(0, lo, CTRL, 0xF, 0xF, true);
  unsigned shi = (unsigned)__builtin_amdgcn_update_dpp(0, hi, CTRL, 0xF, 0xF, true);
  unsigned long long o = ((unsigned long long)shi << 32) | (unsigned long long)slo;
  return k > o ? k : o;
}

// ---------------- FPS v5: bound-pruned, latency-tuned serial chain ---------
// 512 threads (8 waves), 16 sorted points/thread in 2 prune-groups of 8.
// Per-iteration chain: wave bbox skip (__any over per-lane prefix max) ->
// exact group updates -> DPP wave max (VALU, no ds_bpermute) -> lane63 LDS
// store -> barrier -> 4x ds_read_b128 + 7-op register tree -> coord fetch.
// Centers buffered in LDS (aliases dead sort scratch) so the loop issues NO
// global memory ops -> the barrier's vmcnt drain is free.
// Selection chain bit-identical to the r13-verified one: same d2fma, same
// fminf, u64 key (bits(d)<<32 | ~idx) max with first-global-index tie-break.
__global__ __launch_bounds__(512) void fps_kernel(
    const float* __restrict__ x, const int* __restrict__ first_idx,
    float* __restrict__ centers) {   // = d_out[0 .. B*M*3), FLOAT32
  const int b = blockIdx.x;
  const int t = threadIdx.x;
  const int lane = t & 63;
  const int wv = t >> 6;             // wave 0..7
  const float* xb = x + (size_t)b * N_ * 3;

  __shared__ float s_xyz[N_ * 3];                  // 96 KB coord cache
  __shared__ __align__(16) char s_mem[32768];      // hist+perm, later center buf
  __shared__ __align__(16) unsigned long long s_wkey[2][8];
  __shared__ int s_wsum[8];
  __shared__ float s_bb[8][6];

  int* s_hist = (int*)s_mem;                              // 4096 ints
  unsigned short* s_perm = (unsigned short*)(s_mem + 16384);  // 8192 shorts
  float* s_cbuf = (float*)s_mem;                          // 6144 floats (after sort)

  // stage coords: 24576 floats = 6144 float4, coalesced, 12 per thread
  {
    const float4* src = (const float4*)xb;
    float4* dst = (float4*)s_xyz;
#pragma unroll
    for (int i = 0; i < 12; ++i) {
      int e = t + i * 512;
      dst[e] = src[e];
    }
  }
  for (int i = t; i < 4096; i += 512) s_hist[i] = 0;
  __syncthreads();

  // ---- batch bbox (any enclosing box is correct; used only for binning) ----
  float bx0 = INFINITY, bx1 = -INFINITY, by0 = INFINITY, by1 = -INFINITY,
        bz0 = INFINITY, bz1 = -INFINITY;
#pragma unroll
  for (int i = 0; i < 16; ++i) {
    int p = t + i * 512;
    float X = s_xyz[p * 3 + 0], Y = s_xyz[p * 3 + 1], Z = s_xyz[p * 3 + 2];
    bx0 = fminf(bx0, X); bx1 = fmaxf(bx1, X);
    by0 = fminf(by0, Y); by1 = fmaxf(by1, Y);
    bz0 = fminf(bz0, Z); bz1 = fmaxf(bz1, Z);
  }
#pragma unroll
  for (int off = 1; off < 64; off <<= 1) {
    bx0 = fminf(bx0, __shfl_xor(bx0, off)); bx1 = fmaxf(bx1, __shfl_xor(bx1, off));
    by0 = fminf(by0, __shfl_xor(by0, off)); by1 = fmaxf(by1, __shfl_xor(by1, off));
    bz0 = fminf(bz0, __shfl_xor(bz0, off)); bz1 = fmaxf(bz1, __shfl_xor(bz1, off));
  }
  if (lane == 0) {
    s_bb[wv][0] = bx0; s_bb[wv][1] = bx1; s_bb[wv][2] = by0;
    s_bb[wv][3] = by1; s_bb[wv][4] = bz0; s_bb[wv][5] = bz1;
  }
  __syncthreads();
#pragma unroll
  for (int w = 0; w < 8; ++w) {
    bx0 = fminf(bx0, s_bb[w][0]); bx1 = fmaxf(bx1, s_bb[w][1]);
    by0 = fminf(by0, s_bb[w][2]); by1 = fmaxf(by1, s_bb[w][3]);
    bz0 = fminf(bz0, s_bb[w][4]); bz1 = fmaxf(bz1, s_bb[w][5]);
  }
  const float kS = 16.0f * (1.0f - 1e-6f);
  float rx = bx1 - bx0, ry = by1 - by0, rz = bz1 - bz0;
  float sxv = rx > 0.f ? kS / rx : 0.f;
  float syv = ry > 0.f ? kS / ry : 0.f;
  float szv = rz > 0.f ? kS / rz : 0.f;

  // ---- histogram (12-bit Morton cells) ----
#pragma unroll
  for (int i = 0; i < 16; ++i) {
    int p = t + i * 512;
    int qx = (int)((s_xyz[p * 3 + 0] - bx0) * sxv);
    int qy = (int)((s_xyz[p * 3 + 1] - by0) * syv);
    int qz = (int)((s_xyz[p * 3 + 2] - bz0) * szv);
    qx = qx < 0 ? 0 : (qx > 15 ? 15 : qx);
    qy = qy < 0 ? 0 : (qy > 15 ? 15 : qy);
    qz = qz < 0 ? 0 : (qz > 15 ? 15 : qz);
    int c = msp4(qx) | (msp4(qy) << 1) | (msp4(qz) << 2);
    atomicAdd(&s_hist[c], 1);
  }
  __syncthreads();

  // ---- exclusive scan over 4096 bins (thread owns bins [8t,8t+8)) ----
  {
    int h[8], pre[8];
    int acc = 0;
#pragma unroll
    for (int i = 0; i < 8; ++i) { h[i] = s_hist[t * 8 + i]; pre[i] = acc; acc += h[i]; }
    int incl = acc;
#pragma unroll
    for (int off = 1; off < 64; off <<= 1) {
      int v = __shfl_up(incl, off);
      if (lane >= off) incl += v;
    }
    int texcl = incl - acc;
    if (lane == 63) s_wsum[wv] = incl;
    __syncthreads();
    int woff = 0;
#pragma unroll
    for (int w = 0; w < 8; ++w) woff += (w < wv) ? s_wsum[w] : 0;
#pragma unroll
    for (int i = 0; i < 8; ++i) s_hist[t * 8 + i] = woff + texcl + pre[i];
  }
  __syncthreads();

  // ---- scatter: s_perm[pos] = original point index ----
#pragma unroll
  for (int i = 0; i < 16; ++i) {
    int p = t + i * 512;
    int qx = (int)((s_xyz[p * 3 + 0] - bx0) * sxv);
    int qy = (int)((s_xyz[p * 3 + 1] - by0) * syv);
    int qz = (int)((s_xyz[p * 3 + 2] - bz0) * szv);
    qx = qx < 0 ? 0 : (qx > 15 ? 15 : qx);
    qy = qy < 0 ? 0 : (qy > 15 ? 15 : qy);
    qz = qz < 0 ? 0 : (qz > 15 ? 15 : qz);
    int c = msp4(qx) | (msp4(qy) << 1) | (msp4(qz) << 2);
    int pos = atomicAdd(&s_hist[c], 1);
    s_perm[pos] = (unsigned short)p;
  }
  __syncthreads();

  // ---- load 16 sorted slots/thread; build 2 group bboxes (8 pts each) ----
  float px[16], py[16], pz[16], d[16];
  unsigned lo32[16];
  float gx0[2], gx1[2], gy0[2], gy1[2], gz0[2], gz1[2];
#pragma unroll
  for (int g = 0; g < 2; ++g) {
    gx0[g] = INFINITY; gx1[g] = -INFINITY; gy0[g] = INFINITY;
    gy1[g] = -INFINITY; gz0[g] = INFINITY; gz1[g] = -INFINITY;
  }
#pragma unroll
  for (int i = 0; i < 16; ++i) {
    int p = (int)s_perm[t * 16 + i];
    int g = i >> 3;
    px[i] = s_xyz[p * 3 + 0];
    py[i] = s_xyz[p * 3 + 1];
    pz[i] = s_xyz[p * 3 + 2];
    d[i] = INFINITY;   // fminf(inf, v) == v exactly -> first update installs d0
    lo32[i] = 0xFFFFFFFFu - (unsigned)p;
    gx0[g] = fminf(gx0[g], px[i]); gx1[g] = fmaxf(gx1[g], px[i]);
    gy0[g] = fminf(gy0[g], py[i]); gy1[g] = fmaxf(gy1[g], py[i]);
    gz0[g] = fminf(gz0[g], pz[i]); gz1[g] = fmaxf(gz1[g], pz[i]);
  }
  // wave bbox (uniform across lanes after butterfly)
  float wx0 = fminf(gx0[0], gx0[1]), wx1 = fmaxf(gx1[0], gx1[1]);
  float wy0 = fminf(gy0[0], gy0[1]), wy1 = fmaxf(gy1[0], gy1[1]);
  float wz0 = fminf(gz0[0], gz0[1]), wz1 = fmaxf(gz1[0], gz1[1]);
#pragma unroll
  for (int off = 1; off < 64; off <<= 1) {
    wx0 = fminf(wx0, __shfl_xor(wx0, off)); wx1 = fmaxf(wx1, __shfl_xor(wx1, off));
    wy0 = fminf(wy0, __shfl_xor(wy0, off)); wy1 = fmaxf(wy1, __shfl_xor(wy1, off));
    wz0 = fminf(wz0, __shfl_xor(wz0, off)); wz1 = fmaxf(wz1, __shfl_xor(wz1, off));
  }

  int fi = first_idx[b];
  float ncx = s_xyz[fi * 3 + 0], ncy = s_xyz[fi * 3 + 1], ncz = s_xyz[fi * 3 + 2];
  if (t == 0) {   // hist region is dead now; s_cbuf aliases it
    s_cbuf[0] = ncx; s_cbuf[1] = ncy; s_cbuf[2] = ncz;
  }

  unsigned long long gkey[2];
  gkey[0] = 0x7F800000ULL << 32;   // inf max-d, lo=0
  gkey[1] = 0x7F800000ULL << 32;
  unsigned long long wk = 0x7F800000ULL << 32;  // per-lane cached prefix max

  for (int it = 1; it < M_; ++it) {
    // wave-level conservative bound. wk is a per-lane prefix max that always
    // includes the lane's own keys, so a lane passing the skip test proves
    // its own points need no update; __any makes the branch uniform.
    float wdx = fmaxf(fmaxf(wx0 - ncx, ncx - wx1), 0.f);
    float wdy = fmaxf(fmaxf(wy0 - ncy, ncy - wy1), 0.f);
    float wdz = fmaxf(fmaxf(wz0 - ncz, ncz - wz1), 0.f);
    float wlb = __builtin_fmaf(wdz, wdz, __builtin_fmaf(wdy, wdy, wdx * wdx));
    float wgm = __builtin_bit_cast(float, (unsigned)(wk >> 32));
    if (__any(wlb * 0.999f < wgm)) {
#pragma unroll
      for (int g = 0; g < 2; ++g) {
        float gdx = fmaxf(fmaxf(gx0[g] - ncx, ncx - gx1[g]), 0.f);
        float gdy = fmaxf(fmaxf(gy0[g] - ncy, ncy - gy1[g]), 0.f);
        float gdz = fmaxf(fmaxf(gz0[g] - ncz, ncz - gz1[g]), 0.f);
        float glb = __builtin_fmaf(gdz, gdz, __builtin_fmaf(gdy, gdy, gdx * gdx));
        float ggm = __builtin_bit_cast(float, (unsigned)(gkey[g] >> 32));
        if (glb * 0.999f < ggm) {
          unsigned long long k[8];
#pragma unroll
          for (int i = 0; i < 8; ++i) {
            int s = g * 8 + i;
            float dd = d2fma(px[s], py[s], pz[s], ncx, ncy, ncz);
            float dm = fminf(d[s], dd);
            d[s] = dm;
            k[i] = ((unsigned long long)__builtin_bit_cast(unsigned, dm) << 32) |
                   (unsigned long long)lo32[s];
          }
#pragma unroll
          for (int sd = 4; sd >= 1; sd >>= 1)
#pragma unroll
            for (int i = 0; i < sd; ++i)
              k[i] = k[i] > k[i + sd] ? k[i] : k[i + sd];
          gkey[g] = k[0];
        }
      }
      // DPP wave max (VALU-only): lane63 ends with the full 64-lane max;
      // every lane holds a prefix max that includes itself.
      unsigned long long kk = gkey[0] > gkey[1] ? gkey[0] : gkey[1];
      kk = dpp_umax64<0x111>(kk);   // row_shr:1
      kk = dpp_umax64<0x112>(kk);   // row_shr:2
      kk = dpp_umax64<0x114>(kk);   // row_shr:4
      kk = dpp_umax64<0x118>(kk);   // row_shr:8
      kk = dpp_umax64<0x142>(kk);   // row_bcast:15
      kk = dpp_umax64<0x143>(kk);   // row_bcast:31
      wk = kk;
    }
    if (lane == 63) s_wkey[it & 1][wv] = wk;
    __syncthreads();
    // cross-wave: 4 broadcast ds_read_b128 (parallel latency) + register tree
    {
      const ulonglong2* sp = (const ulonglong2*)(&s_wkey[it & 1][0]);
      ulonglong2 q0 = sp[0], q1 = sp[1], q2 = sp[2], q3 = sp[3];
      unsigned long long a0 = q0.x > q0.y ? q0.x : q0.y;
      unsigned long long a1 = q1.x > q1.y ? q1.x : q1.y;
      unsigned long long a2 = q2.x > q2.y ? q2.x : q2.y;
      unsigned long long a3 = q3.x > q3.y ? q3.x : q3.y;
      unsigned long long b0 = a0 > a1 ? a0 : a1;
      unsigned long long b1 = a2 > a3 ? a2 : a3;
      unsigned long long gk = b0 > b1 ? b0 : b1;
      int gi = (int)(0xFFFFFFFFu - (unsigned)(gk & 0xFFFFFFFFull));
      int gs = __builtin_amdgcn_readfirstlane(gi);   // uniform index
      ncx = s_xyz[gs * 3 + 0];                        // LDS broadcast fetch
      ncy = s_xyz[gs * 3 + 1];
      ncz = s_xyz[gs * 3 + 2];
    }
    if (t == 0) {
      s_cbuf[it * 3 + 0] = ncx; s_cbuf[it * 3 + 1] = ncy; s_cbuf[it * 3 + 2] = ncz;
    }
    // no second barrier: next iteration writes the other parity buffer
  }

  // bulk center write-out: 6144 floats = 1536 float4, coalesced
  __syncthreads();
  {
    float4* dst = (float4*)(centers + (size_t)b * M_ * 3);
    const float4* src = (const float4*)s_cbuf;
#pragma unroll
    for (int i = 0; i < 3; ++i) dst[t + i * 512] = src[t + i * 512];
  }
}

// ---------------- Ball query: one wave per center -------------------------
#define CAP_ 512
__global__ __launch_bounds__(256) void ballq_kernel(
    const float* __restrict__ x, const float* __restrict__ centers,
    int* __restrict__ nbr) {
  __shared__ float cd[4][CAP_];
  __shared__ int cidx[4][CAP_];
  const int w = threadIdx.x >> 6;
  const int lane = threadIdx.x & 63;
  const int cm = blockIdx.x * 4 + w;
  const int b = cm >> 11;  // / M_
  const float* xb = x + (size_t)b * N_ * 3;
  const float ccx = centers[(size_t)cm * 3 + 0];
  const float ccy = centers[(size_t)cm * 3 + 1];
  const float ccz = centers[(size_t)cm * 3 + 2];
  int count = 0;
  for (int base = 0; base < N_; base += 64) {
    int p = base + lane;
    float d2 = d2fma(xb[p * 3 + 0], xb[p * 3 + 1], xb[p * 3 + 2], ccx, ccy, ccz);
    bool isin = d2 < 0.09f;   // f32(0.3**2), strict <
    unsigned long long m = __ballot(isin);
    if (isin) {
      int pos = count + (int)__popcll(m & ((1ull << lane) - 1ull));
      if (pos < CAP_) { cd[w][pos] = d2; cidx[w][pos] = p; }  // index-ordered = stable
    }
    count += (int)__popcll(m);
  }
  if (count > CAP_) count = CAP_;
  int nw = count < K_ ? count : K_;
  for (int cc = lane; cc < count; cc += 64) {
    float dcc = cd[w][cc];
    int rank = 0;
    for (int j = 0; j < count; ++j) {
      float dj = cd[w][j];
      rank += (dj < dcc || (dj == dcc && j < cc)) ? 1 : 0;  // stable order
    }
    if (rank < K_) nbr[(size_t)cm * K_ + rank] = cidx[w][cc];
  }
  // pad: reference's -1 wraps to N-1 on gather
  for (int s = nw + lane; s < K_; s += 64) nbr[(size_t)cm * K_ + s] = N_ - 1;
}

// ---------------- Pack f32 weights into MFMA B-fragment order (bf16) ------
// B-frag for 16x16x32: lane holds B[k = (lane>>4)*8 + j][n = lane&15].
__global__ __launch_bounds__(256) void pack_kernel(
    const float* __restrict__ w1, const float* __restrict__ w2,
    unsigned short* __restrict__ w1p, unsigned short* __restrict__ w2p) {
  int e = blockIdx.x * 256 + threadIdx.x;
  if (e < 3 * 17 * 64 * 8) {
    int j = e & 7, lane = (e >> 3) & 63, fi = e >> 9;
    int kt = fi / 17, nt = fi - kt * 17;
    int k = kt * 32 + (lane >> 4) * 8 + j;
    int n = nt * 16 + (lane & 15);
    float v = (k < CIN_ && n < HID_) ? w1[k * HID_ + n] : 0.f;
    w1p[e] = f2bf(v);
  } else {
    int e2 = e - 3 * 17 * 64 * 8;
    if (e2 < 9 * 8 * 64 * 8) {
      int j = e2 & 7, lane = (e2 >> 3) & 63, fi = e2 >> 9;
      int kt = fi >> 3, nt = fi & 7;
      int k = kt * 32 + (lane >> 4) * 8 + j;
      int n = nt * 16 + (lane & 15);
      float v = (k < HID_) ? w2[k * OUT_ + n] : 0.f;
      w2p[e2] = f2bf(v);
    }
  }
}

// ---------------- Fused gather + MLP + LN + max, one center at a time -----
__global__ __launch_bounds__(512) void mlp_kernel(
    const float* __restrict__ x, const float* __restrict__ features,
    const float* __restrict__ centers, const int* __restrict__ nbr,
    const unsigned short* __restrict__ w1p, const float* __restrict__ b1,
    const float* __restrict__ g1, const float* __restrict__ be1,
    const unsigned short* __restrict__ w2p, const float* __restrict__ b2,
    const float* __restrict__ g2, const float* __restrict__ be2,
    float* __restrict__ out1) {
  __shared__ __align__(16) unsigned short A1[32 * 104];  // comb bf16, K1pad=96 (+8 pad)
  __shared__ __align__(16) unsigned short H1[32 * 296];  // h1 bf16, K2pad=288 (+8 pad)
  __shared__ float H2[32 * 132];                          // h2 f32 (pre-LN2), +4 pad
  __shared__ float s_sum[32], s_sum2[32], s_mu[32], s_rs[32];
  __shared__ int s_nbr[32];
  __shared__ float s_ctr[3];

  const int tid = threadIdx.x;
  const int lane = tid & 63;
  const int wv = tid >> 6;   // wave 0..7
  const int q4 = lane >> 4;  // quad 0..3
  const int nl = lane & 15;

  for (int e = tid; e < 32 * 104; e += 512) A1[e] = 0;
  for (int e = tid; e < 32 * 296; e += 512) H1[e] = 0;
  __syncthreads();

  for (int cm = blockIdx.x; cm < B_ * M_; cm += gridDim.x) {
    const int b = cm >> 11;
    if (tid < 32) s_nbr[tid] = nbr[(size_t)cm * K_ + tid];
    else if (tid < 64) s_sum[tid - 32] = 0.f;
    else if (tid < 96) s_sum2[tid - 64] = 0.f;
    else if (tid < 99) s_ctr[tid - 96] = centers[(size_t)cm * 3 + (tid - 96)];
    __syncthreads();

    // gather: 16 threads per neighbor row
    {
      int r = tid >> 4, j = tid & 15;
      int idx = s_nbr[r];
      const float4* frow = (const float4*)(features + ((size_t)b * N_ + idx) * C_);
      float4 f4 = frow[j];
      int base = r * 104 + j * 4;
      A1[base + 0] = f2bf(f4.x); A1[base + 1] = f2bf(f4.y);
      A1[base + 2] = f2bf(f4.z); A1[base + 3] = f2bf(f4.w);
      if (j == 0) {
        const float* xp = x + ((size_t)b * N_ + idx) * 3;
        A1[r * 104 + 64] = f2bf(xp[0] - s_ctr[0]);
        A1[r * 104 + 65] = f2bf(xp[1] - s_ctr[1]);
        A1[r * 104 + 66] = f2bf(xp[2] - s_ctr[2]);
      }
    }
    __syncthreads();

    // GEMM1: (32x96) @ (96x272), B-frags register-cached from global
    for (int nt = wv; nt < 17; nt += 8) {
      short8 bfr[3];
#pragma unroll
      for (int kt = 0; kt < 3; ++kt)
        bfr[kt] = *(const short8*)(w1p + (size_t)((kt * 17 + nt) * 64 + lane) * 8);
      int col = nt * 16 + nl;
      bool cok = col < HID_;
      float bias = cok ? b1[col] : 0.f;
#pragma unroll
      for (int mt = 0; mt < 2; ++mt) {
        floatx4 acc = {0.f, 0.f, 0.f, 0.f};
        const unsigned short* ap = A1 + (mt * 16 + nl) * 104 + q4 * 8;
#pragma unroll
        for (int kt = 0; kt < 3; ++kt) {
          short8 a = *(const short8*)(ap + kt * 32);
          acc = __builtin_amdgcn_mfma_f32_16x16x32_bf16(a, bfr[kt], acc, 0, 0, 0);
        }
#pragma unroll
        for (int r = 0; r < 4; ++r) {
          int row = mt * 16 + q4 * 4 + r;
          float g = 0.f;
          if (cok) {
            float v = acc[r] + bias;
            g = gelu_tanh(v);
            H1[row * 296 + col] = f2bf(g);
          }
          float s1 = g, s2 = g * g;
#pragma unroll
          for (int off = 1; off < 16; off <<= 1) {
            s1 += __shfl_xor(s1, off);
            s2 += __shfl_xor(s2, off);
          }
          if (nl == 0) { atomicAdd(&s_sum[row], s1); atomicAdd(&s_sum2[row], s2); }
        }
      }
    }
    __syncthreads();
    if (tid < 32) {
      float mu = s_sum[tid] * (1.f / HID_);
      float var = s_sum2[tid] * (1.f / HID_) - mu * mu;
      s_mu[tid] = mu;
      s_rs[tid] = rsqrtf(var + EPS_);
    }
    __syncthreads();
    // LN1 in place (bf16), zero stats for LN2
    for (int e = tid; e < K_ * HID_; e += 512) {
      int r = e / HID_, c = e - r * HID_;
      float g = bf2f(H1[r * 296 + c]);
      float v = (g - s_mu[r]) * s_rs[r] * g1[c] + be1[c];
      H1[r * 296 + c] = f2bf(v);
    }
    if (tid < 32) { s_sum[tid] = 0.f; s_sum2[tid] = 0.f; }
    __syncthreads();

    // GEMM2: (32x288) @ (288x128), one n-tile per wave
    {
      int nt = wv;
      short8 bfr2[9];
#pragma unroll
      for (int kt = 0; kt < 9; ++kt)
        bfr2[kt] = *(const short8*)(w2p + (size_t)((kt * 8 + nt) * 64 + lane) * 8);
      int col = nt * 16 + nl;
      float bias = b2[col];
#pragma unroll
      for (int mt = 0; mt < 2; ++mt) {
        floatx4 acc = {0.f, 0.f, 0.f, 0.f};
        const unsigned short* ap = H1 + (mt * 16 + nl) * 296 + q4 * 8;
#pragma unroll
        for (int kt = 0; kt < 9; ++kt) {
          short8 a = *(const short8*)(ap + kt * 32);
          acc = __builtin_amdgcn_mfma_f32_16x16x32_bf16(a, bfr2[kt], acc, 0, 0, 0);
        }
#pragma unroll
        for (int r = 0; r < 4; ++r) {
          int row = mt * 16 + q4 * 4 + r;
          float v = acc[r] + bias;
          H2[row * 132 + col] = v;
          float s1 = v, s2 = v * v;
#pragma unroll
          for (int off = 1; off < 16; off <<= 1) {
            s1 += __shfl_xor(s1, off);
            s2 += __shfl_xor(s2, off);
          }
          if (nl == 0) { atomicAdd(&s_sum[row], s1); atomicAdd(&s_sum2[row], s2); }
        }
      }
    }
    __syncthreads();
    if (tid < 32) {
      float mu = s_sum[tid] * (1.f / OUT_);
      float var = s_sum2[tid] * (1.f / OUT_) - mu * mu;
      s_mu[tid] = mu;
      s_rs[tid] = rsqrtf(var + EPS_);
    }
    __syncthreads();
    if (tid < OUT_) {
      int col = tid;
      float gg = g2[col], bb = be2[col];
      float mx = -3.4e38f;
#pragma unroll 4
      for (int r = 0; r < K_; ++r) {
        float v = H2[r * 132 + col];
        float o = (v - s_mu[r]) * s_rs[r] * gg + bb;
        mx = fmaxf(mx, o);
      }
      out1[(size_t)cm * OUT_ + col] = mx;   // FLOAT32 output
    }
    __syncthreads();
  }
}

extern "C" void kernel_launch(void* const* d_in, const int* in_sizes, int n_in,
                              void* d_out, int out_size, void* d_ws, size_t ws_size,
                              hipStream_t stream) {
  const float* x = (const float*)d_in[0];
  const float* features = (const float*)d_in[1];
  const int* first_idx = (const int*)d_in[2];
  const float* w1 = (const float*)d_in[3];
  const float* b1 = (const float*)d_in[4];
  const float* g1 = (const float*)d_in[5];
  const float* be1 = (const float*)d_in[6];
  const float* w2 = (const float*)d_in[7];
  const float* b2 = (const float*)d_in[8];
  const float* g2 = (const float*)d_in[9];
  const float* be2 = (const float*)d_in[10];

  // d_out is FLOAT32: centers (8,2048,3) then out (8,2048,128), concatenated.
  float* centers = (float*)d_out;
  float* out1 = (float*)d_out + (size_t)B_ * M_ * 3;

  // ws layout (bytes): nbr [0,2097152) | w1p [2097152,2149376) | w2p [2149376,2223104)
  int* nbr = (int*)d_ws;
  unsigned short* w1p = (unsigned short*)((char*)d_ws + 2097152);
  unsigned short* w2p = (unsigned short*)((char*)d_ws + 2149376);

  pack_kernel<<<dim3(246), dim3(256), 0, stream>>>(w1, w2, w1p, w2p);
  fps_kernel<<<dim3(B_), dim3(512), 0, stream>>>(x, first_idx, centers);
  ballq_kernel<<<dim3((B_ * M_) / 4), dim3(256), 0, stream>>>(x, centers, nbr);
  mlp_kernel<<<dim3(512), dim3(512), 0, stream>>>(x, features, centers, nbr,
                                                  w1p, b1, g1, be1, w2p, b2, g2, be2, out1);
}

// Round 3
// 3126.160 us; speedup vs baseline: 1.0527x; 1.0527x over previous
//
#include <hip/hip_runtime.h>
#include <hip/hip_bf16.h>
#include <math.h>

#define B_ 8
#define N_ 8192
#define C_ 64
#define M_ 2048
#define K_ 32
#define OUT_ 128
#define CIN_ 67
#define HID_ 268
#define EPS_ 1e-6f
#define CONS_ 240
#define CAPQ_ 512

typedef short short8 __attribute__((ext_vector_type(8)));
typedef float floatx4 __attribute__((ext_vector_type(4)));

__device__ __forceinline__ unsigned short f2bf(float f) {
  unsigned u = __builtin_bit_cast(unsigned, f);
  u += 0x7fffu + ((u >> 16) & 1u);   // RNE (MFMA input casts only)
  return (unsigned short)(u >> 16);
}
__device__ __forceinline__ float bf2f(unsigned short h) {
  return __builtin_bit_cast(float, (unsigned)h << 16);
}

// Reference-matching distance (verified r13, bit-exact): square fused into the
// 3-element reduce as FMA, index-ascending.
__device__ __forceinline__ float d2fma(float ax, float ay, float az,
                                       float bx, float by, float bz) {
#pragma clang fp contract(off)
  float dx = ax - bx, dy = ay - by, dz = az - bz;
  return __builtin_fmaf(dz, dz, __builtin_fmaf(dy, dy, dx * dx));
}

__device__ __forceinline__ float gelu_tanh(float v) {
  const float k0 = 0.7978845608028654f;  // sqrt(2/pi)
  const float k1 = 0.044715f;
  float u = k0 * (v + k1 * v * v * v);
  return 0.5f * v * (1.0f + tanhf(u));
}

// Morton spread of a 4-bit value to bit positions 0,3,6,9
__device__ __forceinline__ int msp4(int v) {
  return (v & 1) | ((v & 2) << 2) | ((v & 4) << 4) | ((v & 8) << 6);
}

// One DPP max step on a u64 key (VALU-only; keys are unsigned so the
// bound_ctrl zero-fill is the identity for max).
template <int CTRL>
__device__ __forceinline__ unsigned long long dpp_umax64(unsigned long long k) {
  int lo = (int)(unsigned)k;
  int hi = (int)(unsigned)(k >> 32);
  unsigned slo = (unsigned)__builtin_amdgcn_update_dpp(0, lo, CTRL, 0xF, 0xF, true);
  unsigned shi = (unsigned)__builtin_amdgcn_update_dpp(0, hi, CTRL, 0xF, 0xF, true);
  unsigned long long o = ((unsigned long long)shi << 32) | (unsigned long long)slo;
  return k > o ? k : o;
}

// ---------------- Pack f32 weights into MFMA B-fragment order (bf16) ------
// Also zeroes the producer-consumer progress flags (runs before fused_kernel
// in stream order every launch).
__global__ __launch_bounds__(256) void pack_kernel(
    const float* __restrict__ w1, const float* __restrict__ w2,
    unsigned short* __restrict__ w1p, unsigned short* __restrict__ w2p,
    int* __restrict__ prog) {
  if (blockIdx.x == 0 && threadIdx.x < B_) prog[threadIdx.x] = 0;
  int e = blockIdx.x * 256 + threadIdx.x;
  if (e < 3 * 17 * 64 * 8) {
    int j = e & 7, lane = (e >> 3) & 63, fi = e >> 9;
    int kt = fi / 17, nt = fi - kt * 17;
    int k = kt * 32 + (lane >> 4) * 8 + j;
    int n = nt * 16 + (lane & 15);
    float v = (k < CIN_ && n < HID_) ? w1[k * HID_ + n] : 0.f;
    w1p[e] = f2bf(v);
  } else {
    int e2 = e - 3 * 17 * 64 * 8;
    if (e2 < 9 * 8 * 64 * 8) {
      int j = e2 & 7, lane = (e2 >> 3) & 63, fi = e2 >> 9;
      int kt = fi >> 3, nt = fi & 7;
      int k = kt * 32 + (lane >> 4) * 8 + j;
      int n = nt * 16 + (lane & 15);
      float v = (k < HID_) ? w2[k * OUT_ + n] : 0.f;
      w2p[e2] = f2bf(v);
    }
  }
}

// ---------------- Fused producer (FPS) + consumer (ballq+MLP) -------------
// Blocks 0..7: FPS (identical math to the R2-verified chain), publishing
// centers in chunks of 32 via agent-scope release stores to prog[b].
// Blocks 8..247: per-center consumers. Spin (acquire) until the center is
// published, then ball-query into LDS (index-ordered, identical to the
// verified ballq) and run the byte-identical MLP+LN+max epilogue.
// Deadlock-free by construction: 131KB LDS -> 1 block/CU; 240 consumers
// occupy <= 240 CUs, leaving >= 8 CUs for FPS regardless of dispatch order.
__global__ __launch_bounds__(512) void fused_kernel(
    const float* __restrict__ x, const float* __restrict__ features,
    const int* __restrict__ first_idx,
    const unsigned short* __restrict__ w1p, const float* __restrict__ b1,
    const float* __restrict__ g1, const float* __restrict__ be1,
    const unsigned short* __restrict__ w2p, const float* __restrict__ b2,
    const float* __restrict__ g2, const float* __restrict__ be2,
    float* __restrict__ centers, float* __restrict__ out1,
    int* __restrict__ prog) {
  __shared__ __align__(16) char smem[131456];
  const int tid = threadIdx.x;
  const int lane = tid & 63;
  const int wv = tid >> 6;   // wave 0..7

  if (blockIdx.x < B_) {
    // ======================= FPS producer =======================
    const int b = blockIdx.x;
    const float* xb = x + (size_t)b * N_ * 3;

    float* s_xyz = (float*)smem;                                   // 98304 B
    char* s_mem = smem + 98304;                                    // 32768 B
    unsigned long long* s_wkey = (unsigned long long*)(smem + 131072);  // [2][8]
    int* s_wsum = (int*)(smem + 131200);                           // 8
    float* s_bb = (float*)(smem + 131232);                         // [8][6]

    int* s_hist = (int*)s_mem;                                     // 4096 ints
    unsigned short* s_perm = (unsigned short*)(s_mem + 16384);     // 8192 shorts
    float* s_cbuf = (float*)s_mem;                                 // 6144 floats (after sort)

    // stage coords: 24576 floats = 6144 float4, coalesced, 12 per thread
    {
      const float4* src = (const float4*)xb;
      float4* dst = (float4*)s_xyz;
#pragma unroll
      for (int i = 0; i < 12; ++i) {
        int e = tid + i * 512;
        dst[e] = src[e];
      }
    }
    for (int i = tid; i < 4096; i += 512) s_hist[i] = 0;
    __syncthreads();

    // ---- batch bbox (any enclosing box is correct; used only for binning) ----
    float bx0 = INFINITY, bx1 = -INFINITY, by0 = INFINITY, by1 = -INFINITY,
          bz0 = INFINITY, bz1 = -INFINITY;
#pragma unroll
    for (int i = 0; i < 16; ++i) {
      int p = tid + i * 512;
      float X = s_xyz[p * 3 + 0], Y = s_xyz[p * 3 + 1], Z = s_xyz[p * 3 + 2];
      bx0 = fminf(bx0, X); bx1 = fmaxf(bx1, X);
      by0 = fminf(by0, Y); by1 = fmaxf(by1, Y);
      bz0 = fminf(bz0, Z); bz1 = fmaxf(bz1, Z);
    }
#pragma unroll
    for (int off = 1; off < 64; off <<= 1) {
      bx0 = fminf(bx0, __shfl_xor(bx0, off)); bx1 = fmaxf(bx1, __shfl_xor(bx1, off));
      by0 = fminf(by0, __shfl_xor(by0, off)); by1 = fmaxf(by1, __shfl_xor(by1, off));
      bz0 = fminf(bz0, __shfl_xor(bz0, off)); bz1 = fmaxf(bz1, __shfl_xor(bz1, off));
    }
    if (lane == 0) {
      s_bb[wv * 6 + 0] = bx0; s_bb[wv * 6 + 1] = bx1; s_bb[wv * 6 + 2] = by0;
      s_bb[wv * 6 + 3] = by1; s_bb[wv * 6 + 4] = bz0; s_bb[wv * 6 + 5] = bz1;
    }
    __syncthreads();
#pragma unroll
    for (int w = 0; w < 8; ++w) {
      bx0 = fminf(bx0, s_bb[w * 6 + 0]); bx1 = fmaxf(bx1, s_bb[w * 6 + 1]);
      by0 = fminf(by0, s_bb[w * 6 + 2]); by1 = fmaxf(by1, s_bb[w * 6 + 3]);
      bz0 = fminf(bz0, s_bb[w * 6 + 4]); bz1 = fmaxf(bz1, s_bb[w * 6 + 5]);
    }
    const float kS = 16.0f * (1.0f - 1e-6f);
    float rx = bx1 - bx0, ry = by1 - by0, rz = bz1 - bz0;
    float sxv = rx > 0.f ? kS / rx : 0.f;
    float syv = ry > 0.f ? kS / ry : 0.f;
    float szv = rz > 0.f ? kS / rz : 0.f;

    // ---- histogram (12-bit Morton cells) ----
#pragma unroll
    for (int i = 0; i < 16; ++i) {
      int p = tid + i * 512;
      int qx = (int)((s_xyz[p * 3 + 0] - bx0) * sxv);
      int qy = (int)((s_xyz[p * 3 + 1] - by0) * syv);
      int qz = (int)((s_xyz[p * 3 + 2] - bz0) * szv);
      qx = qx < 0 ? 0 : (qx > 15 ? 15 : qx);
      qy = qy < 0 ? 0 : (qy > 15 ? 15 : qy);
      qz = qz < 0 ? 0 : (qz > 15 ? 15 : qz);
      int c = msp4(qx) | (msp4(qy) << 1) | (msp4(qz) << 2);
      atomicAdd(&s_hist[c], 1);
    }
    __syncthreads();

    // ---- exclusive scan over 4096 bins (thread owns bins [8t,8t+8)) ----
    {
      int h[8], pre[8];
      int acc = 0;
#pragma unroll
      for (int i = 0; i < 8; ++i) { h[i] = s_hist[tid * 8 + i]; pre[i] = acc; acc += h[i]; }
      int incl = acc;
#pragma unroll
      for (int off = 1; off < 64; off <<= 1) {
        int v = __shfl_up(incl, off);
        if (lane >= off) incl += v;
      }
      int texcl = incl - acc;
      if (lane == 63) s_wsum[wv] = incl;
      __syncthreads();
      int woff = 0;
#pragma unroll
      for (int w = 0; w < 8; ++w) woff += (w < wv) ? s_wsum[w] : 0;
#pragma unroll
      for (int i = 0; i < 8; ++i) s_hist[tid * 8 + i] = woff + texcl + pre[i];
    }
    __syncthreads();

    // ---- scatter: s_perm[pos] = original point index ----
#pragma unroll
    for (int i = 0; i < 16; ++i) {
      int p = tid + i * 512;
      int qx = (int)((s_xyz[p * 3 + 0] - bx0) * sxv);
      int qy = (int)((s_xyz[p * 3 + 1] - by0) * syv);
      int qz = (int)((s_xyz[p * 3 + 2] - bz0) * szv);
      qx = qx < 0 ? 0 : (qx > 15 ? 15 : qx);
      qy = qy < 0 ? 0 : (qy > 15 ? 15 : qy);
      qz = qz < 0 ? 0 : (qz > 15 ? 15 : qz);
      int c = msp4(qx) | (msp4(qy) << 1) | (msp4(qz) << 2);
      int pos = atomicAdd(&s_hist[c], 1);
      s_perm[pos] = (unsigned short)p;
    }
    __syncthreads();

    // ---- load 16 sorted slots/thread; build 2 group bboxes (8 pts each) ----
    float px[16], py[16], pz[16], d[16];
    unsigned lo32[16];
    float gx0[2], gx1[2], gy0[2], gy1[2], gz0[2], gz1[2];
#pragma unroll
    for (int g = 0; g < 2; ++g) {
      gx0[g] = INFINITY; gx1[g] = -INFINITY; gy0[g] = INFINITY;
      gy1[g] = -INFINITY; gz0[g] = INFINITY; gz1[g] = -INFINITY;
    }
#pragma unroll
    for (int i = 0; i < 16; ++i) {
      int p = (int)s_perm[tid * 16 + i];
      int g = i >> 3;
      px[i] = s_xyz[p * 3 + 0];
      py[i] = s_xyz[p * 3 + 1];
      pz[i] = s_xyz[p * 3 + 2];
      d[i] = INFINITY;   // fminf(inf, v) == v exactly -> first update installs d0
      lo32[i] = 0xFFFFFFFFu - (unsigned)p;
      gx0[g] = fminf(gx0[g], px[i]); gx1[g] = fmaxf(gx1[g], px[i]);
      gy0[g] = fminf(gy0[g], py[i]); gy1[g] = fmaxf(gy1[g], py[i]);
      gz0[g] = fminf(gz0[g], pz[i]); gz1[g] = fmaxf(gz1[g], pz[i]);
    }
    // wave bbox (uniform across lanes after butterfly)
    float wx0 = fminf(gx0[0], gx0[1]), wx1 = fmaxf(gx1[0], gx1[1]);
    float wy0 = fminf(gy0[0], gy0[1]), wy1 = fmaxf(gy1[0], gy1[1]);
    float wz0 = fminf(gz0[0], gz0[1]), wz1 = fmaxf(gz1[0], gz1[1]);
#pragma unroll
    for (int off = 1; off < 64; off <<= 1) {
      wx0 = fminf(wx0, __shfl_xor(wx0, off)); wx1 = fmaxf(wx1, __shfl_xor(wx1, off));
      wy0 = fminf(wy0, __shfl_xor(wy0, off)); wy1 = fmaxf(wy1, __shfl_xor(wy1, off));
      wz0 = fminf(wz0, __shfl_xor(wz0, off)); wz1 = fmaxf(wz1, __shfl_xor(wz1, off));
    }

    int fi = first_idx[b];
    float ncx = s_xyz[fi * 3 + 0], ncy = s_xyz[fi * 3 + 1], ncz = s_xyz[fi * 3 + 2];
    if (tid == 0) {   // hist region is dead now; s_cbuf aliases it
      s_cbuf[0] = ncx; s_cbuf[1] = ncy; s_cbuf[2] = ncz;
    }

    unsigned long long gkey[2];
    gkey[0] = 0x7F800000ULL << 32;   // inf max-d, lo=0
    gkey[1] = 0x7F800000ULL << 32;
    unsigned long long wk = 0x7F800000ULL << 32;  // per-lane cached prefix max

    for (int it = 1; it < M_; ++it) {
      // wave-level conservative bound (see R2 notes; __any makes it uniform)
      float wdx = fmaxf(fmaxf(wx0 - ncx, ncx - wx1), 0.f);
      float wdy = fmaxf(fmaxf(wy0 - ncy, ncy - wy1), 0.f);
      float wdz = fmaxf(fmaxf(wz0 - ncz, ncz - wz1), 0.f);
      float wlb = __builtin_fmaf(wdz, wdz, __builtin_fmaf(wdy, wdy, wdx * wdx));
      float wgm = __builtin_bit_cast(float, (unsigned)(wk >> 32));
      if (__any(wlb * 0.999f < wgm)) {
#pragma unroll
        for (int g = 0; g < 2; ++g) {
          float gdx = fmaxf(fmaxf(gx0[g] - ncx, ncx - gx1[g]), 0.f);
          float gdy = fmaxf(fmaxf(gy0[g] - ncy, ncy - gy1[g]), 0.f);
          float gdz = fmaxf(fmaxf(gz0[g] - ncz, ncz - gz1[g]), 0.f);
          float glb = __builtin_fmaf(gdz, gdz, __builtin_fmaf(gdy, gdy, gdx * gdx));
          float ggm = __builtin_bit_cast(float, (unsigned)(gkey[g] >> 32));
          if (glb * 0.999f < ggm) {
            unsigned long long k[8];
#pragma unroll
            for (int i = 0; i < 8; ++i) {
              int s = g * 8 + i;
              float dd = d2fma(px[s], py[s], pz[s], ncx, ncy, ncz);
              float dm = fminf(d[s], dd);
              d[s] = dm;
              k[i] = ((unsigned long long)__builtin_bit_cast(unsigned, dm) << 32) |
                     (unsigned long long)lo32[s];
            }
#pragma unroll
            for (int sd = 4; sd >= 1; sd >>= 1)
#pragma unroll
              for (int i = 0; i < sd; ++i)
                k[i] = k[i] > k[i + sd] ? k[i] : k[i + sd];
            gkey[g] = k[0];
          }
        }
        // DPP wave max (VALU-only): lane63 ends with the full 64-lane max.
        unsigned long long kk = gkey[0] > gkey[1] ? gkey[0] : gkey[1];
        kk = dpp_umax64<0x111>(kk);   // row_shr:1
        kk = dpp_umax64<0x112>(kk);   // row_shr:2
        kk = dpp_umax64<0x114>(kk);   // row_shr:4
        kk = dpp_umax64<0x118>(kk);   // row_shr:8
        kk = dpp_umax64<0x142>(kk);   // row_bcast:15
        kk = dpp_umax64<0x143>(kk);   // row_bcast:31
        wk = kk;
      }
      if (lane == 63) s_wkey[(it & 1) * 8 + wv] = wk;
      __syncthreads();
      // publish chunk (it-32..it): centers already in s_cbuf (writes preceded
      // the barrier we just crossed). Wave 0 flushes; t0 release-stores prog.
      if ((it & 31) == 0) {
        if (wv == 0 && lane < 24) {
          const float4* src = (const float4*)(s_cbuf + (size_t)(it - 32) * 3);
          float4* dst = (float4*)(centers + (size_t)b * M_ * 3 + (size_t)(it - 32) * 3);
          dst[lane] = src[lane];
        }
        if (tid == 0)
          __hip_atomic_store(&prog[b], it, __ATOMIC_RELEASE, __HIP_MEMORY_SCOPE_AGENT);
      }
      // cross-wave: 4 broadcast ds_read_b128 (parallel latency) + register tree
      {
        const ulonglong2* sp = (const ulonglong2*)(&s_wkey[(it & 1) * 8]);
        ulonglong2 q0 = sp[0], q1 = sp[1], q2 = sp[2], q3 = sp[3];
        unsigned long long a0 = q0.x > q0.y ? q0.x : q0.y;
        unsigned long long a1 = q1.x > q1.y ? q1.x : q1.y;
        unsigned long long a2 = q2.x > q2.y ? q2.x : q2.y;
        unsigned long long a3 = q3.x > q3.y ? q3.x : q3.y;
        unsigned long long b0 = a0 > a1 ? a0 : a1;
        unsigned long long b1v = a2 > a3 ? a2 : a3;
        unsigned long long gk = b0 > b1v ? b0 : b1v;
        int gi = (int)(0xFFFFFFFFu - (unsigned)(gk & 0xFFFFFFFFull));
        int gs = __builtin_amdgcn_readfirstlane(gi);   // uniform index
        ncx = s_xyz[gs * 3 + 0];                        // LDS broadcast fetch
        ncy = s_xyz[gs * 3 + 1];
        ncz = s_xyz[gs * 3 + 2];
      }
      if (tid == 0) {
        s_cbuf[it * 3 + 0] = ncx; s_cbuf[it * 3 + 1] = ncy; s_cbuf[it * 3 + 2] = ncz;
      }
      // no second barrier: next iteration writes the other parity buffer
    }

    // final chunk (centers 2016..2047) + completion publish
    __syncthreads();
    if (wv == 0 && lane < 24) {
      const float4* src = (const float4*)(s_cbuf + (size_t)(M_ - 32) * 3);
      float4* dst = (float4*)(centers + (size_t)b * M_ * 3 + (size_t)(M_ - 32) * 3);
      dst[lane] = src[lane];
    }
    if (tid == 0)
      __hip_atomic_store(&prog[b], M_, __ATOMIC_RELEASE, __HIP_MEMORY_SCOPE_AGENT);

  } else {
    // ======================= consumer: ballq + MLP =======================
    unsigned short* A1 = (unsigned short*)smem;            // 32*104 bf16
    unsigned short* H1 = (unsigned short*)(smem + 6656);   // 32*296 bf16
    float* H2 = (float*)(smem + 25600);                    // 32*132 f32
    float* cd = (float*)(smem + 42496);                    // [512]
    int* cidx = (int*)(smem + 44544);                      // [512]
    float* s_sum = (float*)(smem + 46592);
    float* s_sum2 = (float*)(smem + 46720);
    float* s_mu = (float*)(smem + 46848);
    float* s_rs = (float*)(smem + 46976);
    int* s_nbr = (int*)(smem + 47104);                     // [32]
    float* s_ctr = (float*)(smem + 47232);                 // [3]
    int* s_wc = (int*)(smem + 47248);                      // [8]

    const int q4 = lane >> 4;  // quad 0..3
    const int nl = lane & 15;

    for (int e = tid; e < 32 * 104; e += 512) A1[e] = 0;
    for (int e = tid; e < 32 * 296; e += 512) H1[e] = 0;
    __syncthreads();

    for (int cm = (int)blockIdx.x - B_; cm < B_ * M_; cm += CONS_) {
      const int b = cm >> 11;
      const int m = cm & (M_ - 1);
      // wait until center m of batch b is published
      if (tid == 0) {
        while (__hip_atomic_load(&prog[b], __ATOMIC_ACQUIRE,
                                 __HIP_MEMORY_SCOPE_AGENT) <= m)
          __builtin_amdgcn_s_sleep(8);
      }
      __syncthreads();

      if (tid < 32) s_sum[tid] = 0.f;
      else if (tid < 64) s_sum2[tid - 32] = 0.f;
      else if (tid < 67) s_ctr[tid - 64] = centers[(size_t)cm * 3 + (tid - 64)];
      __syncthreads();

      // ---- ball query (index-ordered, identical contents to verified ballq)
      const float* xb = x + (size_t)b * N_ * 3;
      const float ccx = s_ctr[0], ccy = s_ctr[1], ccz = s_ctr[2];
      // pass 1: per-wave in-ball counts over segment [wv*1024, wv*1024+1024)
      int cnt = 0;
      for (int s = 0; s < 16; ++s) {
        int p = wv * 1024 + s * 64 + lane;
        float d2 = d2fma(xb[p * 3 + 0], xb[p * 3 + 1], xb[p * 3 + 2], ccx, ccy, ccz);
        cnt += (int)__popcll(__ballot(d2 < 0.09f));
      }
      if (lane == 0) s_wc[wv] = cnt;
      __syncthreads();
      int base_w = 0, total = 0;
#pragma unroll
      for (int w = 0; w < 8; ++w) {
        int c = s_wc[w];
        base_w += (w < wv) ? c : 0;
        total += c;
      }
      int count = total < CAPQ_ ? total : CAPQ_;
      // pass 2: write (d2, idx) at exact global index-ordered positions
      int pos = base_w;
      for (int s = 0; s < 16; ++s) {
        int p = wv * 1024 + s * 64 + lane;
        float d2 = d2fma(xb[p * 3 + 0], xb[p * 3 + 1], xb[p * 3 + 2], ccx, ccy, ccz);
        bool isin = d2 < 0.09f;   // f32(0.3**2), strict <
        unsigned long long mm = __ballot(isin);
        if (isin) {
          int pp = pos + (int)__popcll(mm & ((1ull << lane) - 1ull));
          if (pp < CAPQ_) { cd[pp] = d2; cidx[pp] = p; }
        }
        pos += (int)__popcll(mm);
      }
      __syncthreads();
      int nw = count < K_ ? count : K_;
      for (int cc = tid; cc < count; cc += 512) {
        float dcc = cd[cc];
        int rank = 0;
        for (int j = 0; j < count; ++j) {
          float dj = cd[j];
          rank += (dj < dcc || (dj == dcc && j < cc)) ? 1 : 0;  // stable order
        }
        if (rank < K_) s_nbr[rank] = cidx[cc];
      }
      for (int s = nw + tid; s < K_; s += 512) s_nbr[s] = N_ - 1;  // pad = N-1
      __syncthreads();

      // ---- gather: 16 threads per neighbor row (byte-identical math)
      {
        int r = tid >> 4, j = tid & 15;
        int idx = s_nbr[r];
        const float4* frow = (const float4*)(features + ((size_t)b * N_ + idx) * C_);
        float4 f4 = frow[j];
        int base = r * 104 + j * 4;
        A1[base + 0] = f2bf(f4.x); A1[base + 1] = f2bf(f4.y);
        A1[base + 2] = f2bf(f4.z); A1[base + 3] = f2bf(f4.w);
        if (j == 0) {
          const float* xp = x + ((size_t)b * N_ + idx) * 3;
          A1[r * 104 + 64] = f2bf(xp[0] - s_ctr[0]);
          A1[r * 104 + 65] = f2bf(xp[1] - s_ctr[1]);
          A1[r * 104 + 66] = f2bf(xp[2] - s_ctr[2]);
        }
      }
      __syncthreads();

      // GEMM1: (32x96) @ (96x272), B-frags register-cached from global
      for (int nt = wv; nt < 17; nt += 8) {
        short8 bfr[3];
#pragma unroll
        for (int kt = 0; kt < 3; ++kt)
          bfr[kt] = *(const short8*)(w1p + (size_t)((kt * 17 + nt) * 64 + lane) * 8);
        int col = nt * 16 + nl;
        bool cok = col < HID_;
        float bias = cok ? b1[col] : 0.f;
#pragma unroll
        for (int mt = 0; mt < 2; ++mt) {
          floatx4 acc = {0.f, 0.f, 0.f, 0.f};
          const unsigned short* ap = A1 + (mt * 16 + nl) * 104 + q4 * 8;
#pragma unroll
          for (int kt = 0; kt < 3; ++kt) {
            short8 a = *(const short8*)(ap + kt * 32);
            acc = __builtin_amdgcn_mfma_f32_16x16x32_bf16(a, bfr[kt], acc, 0, 0, 0);
          }
#pragma unroll
          for (int r = 0; r < 4; ++r) {
            int row = mt * 16 + q4 * 4 + r;
            float g = 0.f;
            if (cok) {
              float v = acc[r] + bias;
              g = gelu_tanh(v);
              H1[row * 296 + col] = f2bf(g);
            }
            float s1 = g, s2 = g * g;
#pragma unroll
            for (int off = 1; off < 16; off <<= 1) {
              s1 += __shfl_xor(s1, off);
              s2 += __shfl_xor(s2, off);
            }
            if (nl == 0) { atomicAdd(&s_sum[row], s1); atomicAdd(&s_sum2[row], s2); }
          }
        }
      }
      __syncthreads();
      if (tid < 32) {
        float mu = s_sum[tid] * (1.f / HID_);
        float var = s_sum2[tid] * (1.f / HID_) - mu * mu;
        s_mu[tid] = mu;
        s_rs[tid] = rsqrtf(var + EPS_);
      }
      __syncthreads();
      // LN1 in place (bf16), zero stats for LN2
      for (int e = tid; e < K_ * HID_; e += 512) {
        int r = e / HID_, c = e - r * HID_;
        float g = bf2f(H1[r * 296 + c]);
        float v = (g - s_mu[r]) * s_rs[r] * g1[c] + be1[c];
        H1[r * 296 + c] = f2bf(v);
      }
      if (tid < 32) { s_sum[tid] = 0.f; s_sum2[tid] = 0.f; }
      __syncthreads();

      // GEMM2: (32x288) @ (288x128), one n-tile per wave
      {
        int nt = wv;
        short8 bfr2[9];
#pragma unroll
        for (int kt = 0; kt < 9; ++kt)
          bfr2[kt] = *(const short8*)(w2p + (size_t)((kt * 8 + nt) * 64 + lane) * 8);
        int col = nt * 16 + nl;
        float bias = b2[col];
#pragma unroll
        for (int mt = 0; mt < 2; ++mt) {
          floatx4 acc = {0.f, 0.f, 0.f, 0.f};
          const unsigned short* ap = H1 + (mt * 16 + nl) * 296 + q4 * 8;
#pragma unroll
          for (int kt = 0; kt < 9; ++kt) {
            short8 a = *(const short8*)(ap + kt * 32);
            acc = __builtin_amdgcn_mfma_f32_16x16x32_bf16(a, bfr2[kt], acc, 0, 0, 0);
          }
#pragma unroll
          for (int r = 0; r < 4; ++r) {
            int row = mt * 16 + q4 * 4 + r;
            float v = acc[r] + bias;
            H2[row * 132 + col] = v;
            float s1 = v, s2 = v * v;
#pragma unroll
            for (int off = 1; off < 16; off <<= 1) {
              s1 += __shfl_xor(s1, off);
              s2 += __shfl_xor(s2, off);
            }
            if (nl == 0) { atomicAdd(&s_sum[row], s1); atomicAdd(&s_sum2[row], s2); }
          }
        }
      }
      __syncthreads();
      if (tid < 32) {
        float mu = s_sum[tid] * (1.f / OUT_);
        float var = s_sum2[tid] * (1.f / OUT_) - mu * mu;
        s_mu[tid] = mu;
        s_rs[tid] = rsqrtf(var + EPS_);
      }
      __syncthreads();
      if (tid < OUT_) {
        int col = tid;
        float gg = g2[col], bb = be2[col];
        float mx = -3.4e38f;
#pragma unroll 4
        for (int r = 0; r < K_; ++r) {
          float v = H2[r * 132 + col];
          float o = (v - s_mu[r]) * s_rs[r] * gg + bb;
          mx = fmaxf(mx, o);
        }
        out1[(size_t)cm * OUT_ + col] = mx;   // FLOAT32 output
      }
      __syncthreads();
    }
  }
}

extern "C" void kernel_launch(void* const* d_in, const int* in_sizes, int n_in,
                              void* d_out, int out_size, void* d_ws, size_t ws_size,
                              hipStream_t stream) {
  const float* x = (const float*)d_in[0];
  const float* features = (const float*)d_in[1];
  const int* first_idx = (const int*)d_in[2];
  const float* w1 = (const float*)d_in[3];
  const float* b1 = (const float*)d_in[4];
  const float* g1 = (const float*)d_in[5];
  const float* be1 = (const float*)d_in[6];
  const float* w2 = (const float*)d_in[7];
  const float* b2 = (const float*)d_in[8];
  const float* g2 = (const float*)d_in[9];
  const float* be2 = (const float*)d_in[10];

  // d_out is FLOAT32: centers (8,2048,3) then out (8,2048,128), concatenated.
  float* centers = (float*)d_out;
  float* out1 = (float*)d_out + (size_t)B_ * M_ * 3;

  // ws layout (bytes): prog [0,32) (old nbr region, now unused) |
  //                    w1p [2097152,2149376) | w2p [2149376,2223104)
  int* prog = (int*)d_ws;
  unsigned short* w1p = (unsigned short*)((char*)d_ws + 2097152);
  unsigned short* w2p = (unsigned short*)((char*)d_ws + 2149376);

  pack_kernel<<<dim3(246), dim3(256), 0, stream>>>(w1, w2, w1p, w2p, prog);
  fused_kernel<<<dim3(B_ + CONS_), dim3(512), 0, stream>>>(
      x, features, first_idx, w1p, b1, g1, be1, w2p, b2, g2, be2,
      centers, out1, prog);
}

// Round 4
// 1942.797 us; speedup vs baseline: 1.6939x; 1.6091x over previous
//
#include <hip/hip_runtime.h>
#include <hip/hip_bf16.h>
#include <math.h>

#define B_ 8
#define N_ 8192
#define C_ 64
#define M_ 2048
#define K_ 32
#define OUT_ 128
#define CIN_ 67
#define HID_ 268
#define EPS_ 1e-6f
#define CONS_ 240      // 8 batches x 30 consumers
#define CAPQ_ 512

typedef short short8 __attribute__((ext_vector_type(8)));
typedef float floatx4 __attribute__((ext_vector_type(4)));

__device__ __forceinline__ unsigned short f2bf(float f) {
  unsigned u = __builtin_bit_cast(unsigned, f);
  u += 0x7fffu + ((u >> 16) & 1u);   // RNE (MFMA input casts only)
  return (unsigned short)(u >> 16);
}
__device__ __forceinline__ float bf2f(unsigned short h) {
  return __builtin_bit_cast(float, (unsigned)h << 16);
}

// Reference-matching distance (verified r13, bit-exact): square fused into the
// 3-element reduce as FMA, index-ascending.
__device__ __forceinline__ float d2fma(float ax, float ay, float az,
                                       float bx, float by, float bz) {
#pragma clang fp contract(off)
  float dx = ax - bx, dy = ay - by, dz = az - bz;
  return __builtin_fmaf(dz, dz, __builtin_fmaf(dy, dy, dx * dx));
}

__device__ __forceinline__ float gelu_tanh(float v) {
  const float k0 = 0.7978845608028654f;  // sqrt(2/pi)
  const float k1 = 0.044715f;
  float u = k0 * (v + k1 * v * v * v);
  return 0.5f * v * (1.0f + tanhf(u));
}

// Morton spread of a 4-bit value to bit positions 0,3,6,9
__device__ __forceinline__ int msp4(int v) {
  return (v & 1) | ((v & 2) << 2) | ((v & 4) << 4) | ((v & 8) << 6);
}

// One DPP max step on a u64 key (VALU-only; keys are unsigned so the
// bound_ctrl zero-fill is the identity for max).
template <int CTRL>
__device__ __forceinline__ unsigned long long dpp_umax64(unsigned long long k) {
  int lo = (int)(unsigned)k;
  int hi = (int)(unsigned)(k >> 32);
  unsigned slo = (unsigned)__builtin_amdgcn_update_dpp(0, lo, CTRL, 0xF, 0xF, true);
  unsigned shi = (unsigned)__builtin_amdgcn_update_dpp(0, hi, CTRL, 0xF, 0xF, true);
  unsigned long long o = ((unsigned long long)shi << 32) | (unsigned long long)slo;
  return k > o ? k : o;
}

// ---------------- Pack f32 weights into MFMA B-fragment order (bf16) ------
// Also zeroes the (cacheline-padded) progress flags before fused_kernel.
__global__ __launch_bounds__(256) void pack_kernel(
    const float* __restrict__ w1, const float* __restrict__ w2,
    unsigned short* __restrict__ w1p, unsigned short* __restrict__ w2p,
    int* __restrict__ prog) {
  if (blockIdx.x == 0) prog[threadIdx.x] = 0;   // 256 ints = 8 padded lines
  int e = blockIdx.x * 256 + threadIdx.x;
  if (e < 3 * 17 * 64 * 8) {
    int j = e & 7, lane = (e >> 3) & 63, fi = e >> 9;
    int kt = fi / 17, nt = fi - kt * 17;
    int k = kt * 32 + (lane >> 4) * 8 + j;
    int n = nt * 16 + (lane & 15);
    float v = (k < CIN_ && n < HID_) ? w1[k * HID_ + n] : 0.f;
    w1p[e] = f2bf(v);
  } else {
    int e2 = e - 3 * 17 * 64 * 8;
    if (e2 < 9 * 8 * 64 * 8) {
      int j = e2 & 7, lane = (e2 >> 3) & 63, fi = e2 >> 9;
      int kt = fi >> 3, nt = fi & 7;
      int k = kt * 32 + (lane >> 4) * 8 + j;
      int n = nt * 16 + (lane & 15);
      float v = (k < HID_) ? w2[k * OUT_ + n] : 0.f;
      w2p[e2] = f2bf(v);
    }
  }
}

// ---------------- Fused producer (FPS) + consumer (ballq+MLP) -------------
// Blocks 0..7: FPS (R2/R3-verified math, untouched), publishing centers in
// chunks of 32 via agent-scope release stores to prog[b*32] (padded line).
// Blocks 8..247: consumers in M-MAJOR order: consumer j owns batch b=j&7,
// lane-group c=j>>3 (30 per batch), and processes center PAIRS
// m={2i,2i+1}, i=c+30k -- always just-published work, no batch-0 stall.
// Each pass ball-queries BOTH centers in one x-scan and runs a 64-row MLP
// (2 centers stacked); per-center arithmetic is byte-identical to the
// verified single-center path.
__global__ __launch_bounds__(512) void fused_kernel(
    const float* __restrict__ x, const float* __restrict__ features,
    const int* __restrict__ first_idx,
    const unsigned short* __restrict__ w1p, const float* __restrict__ b1,
    const float* __restrict__ g1, const float* __restrict__ be1,
    const unsigned short* __restrict__ w2p, const float* __restrict__ b2,
    const float* __restrict__ g2, const float* __restrict__ be2,
    float* __restrict__ centers, float* __restrict__ out1,
    int* __restrict__ prog) {
  __shared__ __align__(16) char smem[131456];
  const int tid = threadIdx.x;
  const int lane = tid & 63;
  const int wv = tid >> 6;   // wave 0..7

  if (blockIdx.x < B_) {
    // ======================= FPS producer =======================
    const int b = blockIdx.x;
    const float* xb = x + (size_t)b * N_ * 3;

    float* s_xyz = (float*)smem;                                   // 98304 B
    char* s_mem = smem + 98304;                                    // 32768 B
    unsigned long long* s_wkey = (unsigned long long*)(smem + 131072);  // [2][8]
    int* s_wsum = (int*)(smem + 131200);                           // 8
    float* s_bb = (float*)(smem + 131232);                         // [8][6]

    int* s_hist = (int*)s_mem;                                     // 4096 ints
    unsigned short* s_perm = (unsigned short*)(s_mem + 16384);     // 8192 shorts
    float* s_cbuf = (float*)s_mem;                                 // 6144 floats (after sort)

    // stage coords: 24576 floats = 6144 float4, coalesced, 12 per thread
    {
      const float4* src = (const float4*)xb;
      float4* dst = (float4*)s_xyz;
#pragma unroll
      for (int i = 0; i < 12; ++i) {
        int e = tid + i * 512;
        dst[e] = src[e];
      }
    }
    for (int i = tid; i < 4096; i += 512) s_hist[i] = 0;
    __syncthreads();

    // ---- batch bbox (any enclosing box is correct; used only for binning) ----
    float bx0 = INFINITY, bx1 = -INFINITY, by0 = INFINITY, by1 = -INFINITY,
          bz0 = INFINITY, bz1 = -INFINITY;
#pragma unroll
    for (int i = 0; i < 16; ++i) {
      int p = tid + i * 512;
      float X = s_xyz[p * 3 + 0], Y = s_xyz[p * 3 + 1], Z = s_xyz[p * 3 + 2];
      bx0 = fminf(bx0, X); bx1 = fmaxf(bx1, X);
      by0 = fminf(by0, Y); by1 = fmaxf(by1, Y);
      bz0 = fminf(bz0, Z); bz1 = fmaxf(bz1, Z);
    }
#pragma unroll
    for (int off = 1; off < 64; off <<= 1) {
      bx0 = fminf(bx0, __shfl_xor(bx0, off)); bx1 = fmaxf(bx1, __shfl_xor(bx1, off));
      by0 = fminf(by0, __shfl_xor(by0, off)); by1 = fmaxf(by1, __shfl_xor(by1, off));
      bz0 = fminf(bz0, __shfl_xor(bz0, off)); bz1 = fmaxf(bz1, __shfl_xor(bz1, off));
    }
    if (lane == 0) {
      s_bb[wv * 6 + 0] = bx0; s_bb[wv * 6 + 1] = bx1; s_bb[wv * 6 + 2] = by0;
      s_bb[wv * 6 + 3] = by1; s_bb[wv * 6 + 4] = bz0; s_bb[wv * 6 + 5] = bz1;
    }
    __syncthreads();
#pragma unroll
    for (int w = 0; w < 8; ++w) {
      bx0 = fminf(bx0, s_bb[w * 6 + 0]); bx1 = fmaxf(bx1, s_bb[w * 6 + 1]);
      by0 = fminf(by0, s_bb[w * 6 + 2]); by1 = fmaxf(by1, s_bb[w * 6 + 3]);
      bz0 = fminf(bz0, s_bb[w * 6 + 4]); bz1 = fmaxf(bz1, s_bb[w * 6 + 5]);
    }
    const float kS = 16.0f * (1.0f - 1e-6f);
    float rx = bx1 - bx0, ry = by1 - by0, rz = bz1 - bz0;
    float sxv = rx > 0.f ? kS / rx : 0.f;
    float syv = ry > 0.f ? kS / ry : 0.f;
    float szv = rz > 0.f ? kS / rz : 0.f;

    // ---- histogram (12-bit Morton cells) ----
#pragma unroll
    for (int i = 0; i < 16; ++i) {
      int p = tid + i * 512;
      int qx = (int)((s_xyz[p * 3 + 0] - bx0) * sxv);
      int qy = (int)((s_xyz[p * 3 + 1] - by0) * syv);
      int qz = (int)((s_xyz[p * 3 + 2] - bz0) * szv);
      qx = qx < 0 ? 0 : (qx > 15 ? 15 : qx);
      qy = qy < 0 ? 0 : (qy > 15 ? 15 : qy);
      qz = qz < 0 ? 0 : (qz > 15 ? 15 : qz);
      int c = msp4(qx) | (msp4(qy) << 1) | (msp4(qz) << 2);
      atomicAdd(&s_hist[c], 1);
    }
    __syncthreads();

    // ---- exclusive scan over 4096 bins (thread owns bins [8t,8t+8)) ----
    {
      int h[8], pre[8];
      int acc = 0;
#pragma unroll
      for (int i = 0; i < 8; ++i) { h[i] = s_hist[tid * 8 + i]; pre[i] = acc; acc += h[i]; }
      int incl = acc;
#pragma unroll
      for (int off = 1; off < 64; off <<= 1) {
        int v = __shfl_up(incl, off);
        if (lane >= off) incl += v;
      }
      int texcl = incl - acc;
      if (lane == 63) s_wsum[wv] = incl;
      __syncthreads();
      int woff = 0;
#pragma unroll
      for (int w = 0; w < 8; ++w) woff += (w < wv) ? s_wsum[w] : 0;
#pragma unroll
      for (int i = 0; i < 8; ++i) s_hist[tid * 8 + i] = woff + texcl + pre[i];
    }
    __syncthreads();

    // ---- scatter: s_perm[pos] = original point index ----
#pragma unroll
    for (int i = 0; i < 16; ++i) {
      int p = tid + i * 512;
      int qx = (int)((s_xyz[p * 3 + 0] - bx0) * sxv);
      int qy = (int)((s_xyz[p * 3 + 1] - by0) * syv);
      int qz = (int)((s_xyz[p * 3 + 2] - bz0) * szv);
      qx = qx < 0 ? 0 : (qx > 15 ? 15 : qx);
      qy = qy < 0 ? 0 : (qy > 15 ? 15 : qy);
      qz = qz < 0 ? 0 : (qz > 15 ? 15 : qz);
      int c = msp4(qx) | (msp4(qy) << 1) | (msp4(qz) << 2);
      int pos = atomicAdd(&s_hist[c], 1);
      s_perm[pos] = (unsigned short)p;
    }
    __syncthreads();

    // ---- load 16 sorted slots/thread; build 2 group bboxes (8 pts each) ----
    float px[16], py[16], pz[16], d[16];
    unsigned lo32[16];
    float gx0[2], gx1[2], gy0[2], gy1[2], gz0[2], gz1[2];
#pragma unroll
    for (int g = 0; g < 2; ++g) {
      gx0[g] = INFINITY; gx1[g] = -INFINITY; gy0[g] = INFINITY;
      gy1[g] = -INFINITY; gz0[g] = INFINITY; gz1[g] = -INFINITY;
    }
#pragma unroll
    for (int i = 0; i < 16; ++i) {
      int p = (int)s_perm[tid * 16 + i];
      int g = i >> 3;
      px[i] = s_xyz[p * 3 + 0];
      py[i] = s_xyz[p * 3 + 1];
      pz[i] = s_xyz[p * 3 + 2];
      d[i] = INFINITY;   // fminf(inf, v) == v exactly -> first update installs d0
      lo32[i] = 0xFFFFFFFFu - (unsigned)p;
      gx0[g] = fminf(gx0[g], px[i]); gx1[g] = fmaxf(gx1[g], px[i]);
      gy0[g] = fminf(gy0[g], py[i]); gy1[g] = fmaxf(gy1[g], py[i]);
      gz0[g] = fminf(gz0[g], pz[i]); gz1[g] = fmaxf(gz1[g], pz[i]);
    }
    // wave bbox (uniform across lanes after butterfly)
    float wx0 = fminf(gx0[0], gx0[1]), wx1 = fmaxf(gx1[0], gx1[1]);
    float wy0 = fminf(gy0[0], gy0[1]), wy1 = fmaxf(gy1[0], gy1[1]);
    float wz0 = fminf(gz0[0], gz0[1]), wz1 = fmaxf(gz1[0], gz1[1]);
#pragma unroll
    for (int off = 1; off < 64; off <<= 1) {
      wx0 = fminf(wx0, __shfl_xor(wx0, off)); wx1 = fmaxf(wx1, __shfl_xor(wx1, off));
      wy0 = fminf(wy0, __shfl_xor(wy0, off)); wy1 = fmaxf(wy1, __shfl_xor(wy1, off));
      wz0 = fminf(wz0, __shfl_xor(wz0, off)); wz1 = fmaxf(wz1, __shfl_xor(wz1, off));
    }

    int fi = first_idx[b];
    float ncx = s_xyz[fi * 3 + 0], ncy = s_xyz[fi * 3 + 1], ncz = s_xyz[fi * 3 + 2];
    if (tid == 0) {   // hist region is dead now; s_cbuf aliases it
      s_cbuf[0] = ncx; s_cbuf[1] = ncy; s_cbuf[2] = ncz;
    }

    unsigned long long gkey[2];
    gkey[0] = 0x7F800000ULL << 32;   // inf max-d, lo=0
    gkey[1] = 0x7F800000ULL << 32;
    unsigned long long wk = 0x7F800000ULL << 32;  // per-lane cached prefix max

    for (int it = 1; it < M_; ++it) {
      // wave-level conservative bound (see R2 notes; __any makes it uniform)
      float wdx = fmaxf(fmaxf(wx0 - ncx, ncx - wx1), 0.f);
      float wdy = fmaxf(fmaxf(wy0 - ncy, ncy - wy1), 0.f);
      float wdz = fmaxf(fmaxf(wz0 - ncz, ncz - wz1), 0.f);
      float wlb = __builtin_fmaf(wdz, wdz, __builtin_fmaf(wdy, wdy, wdx * wdx));
      float wgm = __builtin_bit_cast(float, (unsigned)(wk >> 32));
      if (__any(wlb * 0.999f < wgm)) {
#pragma unroll
        for (int g = 0; g < 2; ++g) {
          float gdx = fmaxf(fmaxf(gx0[g] - ncx, ncx - gx1[g]), 0.f);
          float gdy = fmaxf(fmaxf(gy0[g] - ncy, ncy - gy1[g]), 0.f);
          float gdz = fmaxf(fmaxf(gz0[g] - ncz, ncz - gz1[g]), 0.f);
          float glb = __builtin_fmaf(gdz, gdz, __builtin_fmaf(gdy, gdy, gdx * gdx));
          float ggm = __builtin_bit_cast(float, (unsigned)(gkey[g] >> 32));
          if (glb * 0.999f < ggm) {
            unsigned long long k[8];
#pragma unroll
            for (int i = 0; i < 8; ++i) {
              int s = g * 8 + i;
              float dd = d2fma(px[s], py[s], pz[s], ncx, ncy, ncz);
              float dm = fminf(d[s], dd);
              d[s] = dm;
              k[i] = ((unsigned long long)__builtin_bit_cast(unsigned, dm) << 32) |
                     (unsigned long long)lo32[s];
            }
#pragma unroll
            for (int sd = 4; sd >= 1; sd >>= 1)
#pragma unroll
              for (int i = 0; i < sd; ++i)
                k[i] = k[i] > k[i + sd] ? k[i] : k[i + sd];
            gkey[g] = k[0];
          }
        }
        // DPP wave max (VALU-only): lane63 ends with the full 64-lane max.
        unsigned long long kk = gkey[0] > gkey[1] ? gkey[0] : gkey[1];
        kk = dpp_umax64<0x111>(kk);   // row_shr:1
        kk = dpp_umax64<0x112>(kk);   // row_shr:2
        kk = dpp_umax64<0x114>(kk);   // row_shr:4
        kk = dpp_umax64<0x118>(kk);   // row_shr:8
        kk = dpp_umax64<0x142>(kk);   // row_bcast:15
        kk = dpp_umax64<0x143>(kk);   // row_bcast:31
        wk = kk;
      }
      if (lane == 63) s_wkey[(it & 1) * 8 + wv] = wk;
      __syncthreads();
      // publish chunk [it-32, it): centers already in s_cbuf (writes preceded
      // the barrier just crossed). Wave 0 flushes; t0 release-stores prog.
      if ((it & 31) == 0) {
        if (wv == 0 && lane < 24) {
          const float4* src = (const float4*)(s_cbuf + (size_t)(it - 32) * 3);
          float4* dst = (float4*)(centers + (size_t)b * M_ * 3 + (size_t)(it - 32) * 3);
          dst[lane] = src[lane];
        }
        if (tid == 0)
          __hip_atomic_store(&prog[b * 32], it, __ATOMIC_RELEASE, __HIP_MEMORY_SCOPE_AGENT);
      }
      // cross-wave: 4 broadcast ds_read_b128 (parallel latency) + register tree
      {
        const ulonglong2* sp = (const ulonglong2*)(&s_wkey[(it & 1) * 8]);
        ulonglong2 q0 = sp[0], q1 = sp[1], q2 = sp[2], q3 = sp[3];
        unsigned long long a0 = q0.x > q0.y ? q0.x : q0.y;
        unsigned long long a1 = q1.x > q1.y ? q1.x : q1.y;
        unsigned long long a2 = q2.x > q2.y ? q2.x : q2.y;
        unsigned long long a3 = q3.x > q3.y ? q3.x : q3.y;
        unsigned long long b0 = a0 > a1 ? a0 : a1;
        unsigned long long b1v = a2 > a3 ? a2 : a3;
        unsigned long long gk = b0 > b1v ? b0 : b1v;
        int gi = (int)(0xFFFFFFFFu - (unsigned)(gk & 0xFFFFFFFFull));
        int gs = __builtin_amdgcn_readfirstlane(gi);   // uniform index
        ncx = s_xyz[gs * 3 + 0];                        // LDS broadcast fetch
        ncy = s_xyz[gs * 3 + 1];
        ncz = s_xyz[gs * 3 + 2];
      }
      if (tid == 0) {
        s_cbuf[it * 3 + 0] = ncx; s_cbuf[it * 3 + 1] = ncy; s_cbuf[it * 3 + 2] = ncz;
      }
      // no second barrier: next iteration writes the other parity buffer
    }

    // final chunk (centers 2016..2047) + completion publish
    __syncthreads();
    if (wv == 0 && lane < 24) {
      const float4* src = (const float4*)(s_cbuf + (size_t)(M_ - 32) * 3);
      float4* dst = (float4*)(centers + (size_t)b * M_ * 3 + (size_t)(M_ - 32) * 3);
      dst[lane] = src[lane];
    }
    if (tid == 0)
      __hip_atomic_store(&prog[b * 32], M_, __ATOMIC_RELEASE, __HIP_MEMORY_SCOPE_AGENT);

  } else {
    // ================ consumer: 2-center ballq + 64-row MLP ================
    unsigned short* A1 = (unsigned short*)smem;            // [64][104] bf16
    unsigned short* H1 = (unsigned short*)(smem + 13312);  // [64][296] bf16
    float* H2 = (float*)(smem + 51200);                    // [64][132] f32
    float* cd = (float*)(smem + 84992);                    // [2][512]
    int* cidx = (int*)(smem + 89088);                      // [2][512]
    float* s_sum = (float*)(smem + 93184);                 // [64]
    float* s_sum2 = (float*)(smem + 93440);                // [64]
    float* s_mu = (float*)(smem + 93696);                  // [64]
    float* s_rs = (float*)(smem + 93952);                  // [64]
    int* s_nbr = (int*)(smem + 94208);                     // [64]
    float* s_ctr = (float*)(smem + 94464);                 // [6]
    int* s_wc = (int*)(smem + 94496);                      // [2][8]

    const int j = (int)blockIdx.x - B_;     // 0..239
    const int b = j & 7;                    // owned batch
    const int c = j >> 3;                   // 0..29 within batch
    const int q4 = lane >> 4;  // quad 0..3
    const int nl = lane & 15;

    for (int e = tid; e < 64 * 104; e += 512) A1[e] = 0;
    for (int e = tid; e < 64 * 296; e += 512) H1[e] = 0;
    __syncthreads();

    const float* xb = x + (size_t)b * N_ * 3;

    for (int k35 = 0; k35 < 35; ++k35) {
      int i = c + 30 * k35;                 // pair index, block-uniform
      if (i >= 1024) break;
      const int m0 = 2 * i, m1 = m0 + 1;
      const int cm0 = b * M_ + m0;

      // wait until both centers are published (prog counts centers done)
      if (tid == 0) {
        if (__hip_atomic_load(&prog[b * 32], __ATOMIC_ACQUIRE,
                              __HIP_MEMORY_SCOPE_AGENT) <= m1) {
          do {
            __builtin_amdgcn_s_sleep(16);
          } while (__hip_atomic_load(&prog[b * 32], __ATOMIC_ACQUIRE,
                                     __HIP_MEMORY_SCOPE_AGENT) <= m1);
        }
      }
      __syncthreads();

      if (tid < 64) s_sum[tid] = 0.f;
      else if (tid < 128) s_sum2[tid - 64] = 0.f;
      else if (tid < 134) s_ctr[tid - 128] = centers[(size_t)cm0 * 3 + (tid - 128)];
      __syncthreads();

      const float c0x = s_ctr[0], c0y = s_ctr[1], c0z = s_ctr[2];
      const float c1x = s_ctr[3], c1y = s_ctr[4], c1z = s_ctr[5];

      // ---- ball query, both centers, one x-scan (index-ordered, verified)
      int cnt0 = 0, cnt1 = 0;
      for (int s = 0; s < 16; ++s) {
        int p = wv * 1024 + s * 64 + lane;
        float X = xb[p * 3 + 0], Y = xb[p * 3 + 1], Z = xb[p * 3 + 2];
        float d20 = d2fma(X, Y, Z, c0x, c0y, c0z);
        float d21 = d2fma(X, Y, Z, c1x, c1y, c1z);
        cnt0 += (int)__popcll(__ballot(d20 < 0.09f));
        cnt1 += (int)__popcll(__ballot(d21 < 0.09f));
      }
      if (lane == 0) { s_wc[wv] = cnt0; s_wc[8 + wv] = cnt1; }
      __syncthreads();
      int base0 = 0, tot0 = 0, base1 = 0, tot1 = 0;
#pragma unroll
      for (int w = 0; w < 8; ++w) {
        int v0 = s_wc[w], v1 = s_wc[8 + w];
        base0 += (w < wv) ? v0 : 0; tot0 += v0;
        base1 += (w < wv) ? v1 : 0; tot1 += v1;
      }
      int count0 = tot0 < CAPQ_ ? tot0 : CAPQ_;
      int count1 = tot1 < CAPQ_ ? tot1 : CAPQ_;
      // pass 2: write (d2, idx) at exact global index-ordered positions
      int pos0 = base0, pos1 = base1;
      for (int s = 0; s < 16; ++s) {
        int p = wv * 1024 + s * 64 + lane;
        float X = xb[p * 3 + 0], Y = xb[p * 3 + 1], Z = xb[p * 3 + 2];
        float d20 = d2fma(X, Y, Z, c0x, c0y, c0z);
        float d21 = d2fma(X, Y, Z, c1x, c1y, c1z);
        bool in0 = d20 < 0.09f;   // f32(0.3**2), strict <
        bool in1 = d21 < 0.09f;
        unsigned long long m0m = __ballot(in0);
        unsigned long long m1m = __ballot(in1);
        if (in0) {
          int pp = pos0 + (int)__popcll(m0m & ((1ull << lane) - 1ull));
          if (pp < CAPQ_) { cd[pp] = d20; cidx[pp] = p; }
        }
        if (in1) {
          int pp = pos1 + (int)__popcll(m1m & ((1ull << lane) - 1ull));
          if (pp < CAPQ_) { cd[CAPQ_ + pp] = d21; cidx[CAPQ_ + pp] = p; }
        }
        pos0 += (int)__popcll(m0m);
        pos1 += (int)__popcll(m1m);
      }
      __syncthreads();
      // rank-select K nearest per center (stable order), 256 threads each
      {
        int q = tid >> 8;                  // 0 or 1
        int lt = tid & 255;
        int cnt = q ? count1 : count0;
        int nw = cnt < K_ ? cnt : K_;
        const float* cdq = cd + q * CAPQ_;
        const int* cxq = cidx + q * CAPQ_;
        for (int cc = lt; cc < cnt; cc += 256) {
          float dcc = cdq[cc];
          int rank = 0;
          for (int jj = 0; jj < cnt; ++jj) {
            float dj = cdq[jj];
            rank += (dj < dcc || (dj == dcc && jj < cc)) ? 1 : 0;  // stable
          }
          if (rank < K_) s_nbr[q * K_ + rank] = cxq[cc];
        }
        for (int s = nw + lt; s < K_; s += 256) s_nbr[q * K_ + s] = N_ - 1;
      }
      __syncthreads();

      // ---- gather: 16 threads per neighbor row, 64 rows in 2 halves
#pragma unroll
      for (int h = 0; h < 2; ++h) {
        int rr = (tid >> 4) + h * 32;      // row 0..63
        int jj = tid & 15;
        int q = rr >> 5;
        int idx = s_nbr[rr];
        const float4* frow = (const float4*)(features + ((size_t)b * N_ + idx) * C_);
        float4 f4 = frow[jj];
        int base = rr * 104 + jj * 4;
        A1[base + 0] = f2bf(f4.x); A1[base + 1] = f2bf(f4.y);
        A1[base + 2] = f2bf(f4.z); A1[base + 3] = f2bf(f4.w);
        if (jj == 0) {
          const float* xp = x + ((size_t)b * N_ + idx) * 3;
          A1[rr * 104 + 64] = f2bf(xp[0] - s_ctr[q * 3 + 0]);
          A1[rr * 104 + 65] = f2bf(xp[1] - s_ctr[q * 3 + 1]);
          A1[rr * 104 + 66] = f2bf(xp[2] - s_ctr[q * 3 + 2]);
        }
      }
      __syncthreads();

      // GEMM1: (64x96) @ (96x272), B-frags register-cached from global
      for (int nt = wv; nt < 17; nt += 8) {
        short8 bfr[3];
#pragma unroll
        for (int kt = 0; kt < 3; ++kt)
          bfr[kt] = *(const short8*)(w1p + (size_t)((kt * 17 + nt) * 64 + lane) * 8);
        int col = nt * 16 + nl;
        bool cok = col < HID_;
        float bias = cok ? b1[col] : 0.f;
#pragma unroll
        for (int mt = 0; mt < 4; ++mt) {
          floatx4 acc = {0.f, 0.f, 0.f, 0.f};
          const unsigned short* ap = A1 + (mt * 16 + nl) * 104 + q4 * 8;
#pragma unroll
          for (int kt = 0; kt < 3; ++kt) {
            short8 a = *(const short8*)(ap + kt * 32);
            acc = __builtin_amdgcn_mfma_f32_16x16x32_bf16(a, bfr[kt], acc, 0, 0, 0);
          }
#pragma unroll
          for (int r = 0; r < 4; ++r) {
            int row = mt * 16 + q4 * 4 + r;
            float g = 0.f;
            if (cok) {
              float v = acc[r] + bias;
              g = gelu_tanh(v);
              H1[row * 296 + col] = f2bf(g);
            }
            float s1 = g, s2 = g * g;
#pragma unroll
            for (int off = 1; off < 16; off <<= 1) {
              s1 += __shfl_xor(s1, off);
              s2 += __shfl_xor(s2, off);
            }
            if (nl == 0) { atomicAdd(&s_sum[row], s1); atomicAdd(&s_sum2[row], s2); }
          }
        }
      }
      __syncthreads();
      if (tid < 64) {
        float mu = s_sum[tid] * (1.f / HID_);
        float var = s_sum2[tid] * (1.f / HID_) - mu * mu;
        s_mu[tid] = mu;
        s_rs[tid] = rsqrtf(var + EPS_);
      }
      __syncthreads();
      // LN1 in place (bf16), zero stats for LN2
      for (int e = tid; e < 64 * HID_; e += 512) {
        int r = e / HID_, cc = e - r * HID_;
        float g = bf2f(H1[r * 296 + cc]);
        float v = (g - s_mu[r]) * s_rs[r] * g1[cc] + be1[cc];
        H1[r * 296 + cc] = f2bf(v);
      }
      if (tid < 64) { s_sum[tid] = 0.f; s_sum2[tid] = 0.f; }
      __syncthreads();

      // GEMM2: (64x288) @ (288x128), one n-tile per wave
      {
        int nt = wv;
        short8 bfr2[9];
#pragma unroll
        for (int kt = 0; kt < 9; ++kt)
          bfr2[kt] = *(const short8*)(w2p + (size_t)((kt * 8 + nt) * 64 + lane) * 8);
        int col = nt * 16 + nl;
        float bias = b2[col];
#pragma unroll
        for (int mt = 0; mt < 4; ++mt) {
          floatx4 acc = {0.f, 0.f, 0.f, 0.f};
          const unsigned short* ap = H1 + (mt * 16 + nl) * 296 + q4 * 8;
#pragma unroll
          for (int kt = 0; kt < 9; ++kt) {
            short8 a = *(const short8*)(ap + kt * 32);
            acc = __builtin_amdgcn_mfma_f32_16x16x32_bf16(a, bfr2[kt], acc, 0, 0, 0);
          }
#pragma unroll
          for (int r = 0; r < 4; ++r) {
            int row = mt * 16 + q4 * 4 + r;
            float v = acc[r] + bias;
            H2[row * 132 + col] = v;
            float s1 = v, s2 = v * v;
#pragma unroll
            for (int off = 1; off < 16; off <<= 1) {
              s1 += __shfl_xor(s1, off);
              s2 += __shfl_xor(s2, off);
            }
            if (nl == 0) { atomicAdd(&s_sum[row], s1); atomicAdd(&s_sum2[row], s2); }
          }
        }
      }
      __syncthreads();
      if (tid < 64) {
        float mu = s_sum[tid] * (1.f / OUT_);
        float var = s_sum2[tid] * (1.f / OUT_) - mu * mu;
        s_mu[tid] = mu;
        s_rs[tid] = rsqrtf(var + EPS_);
      }
      __syncthreads();
      if (tid < 256) {
        int q = tid >> 7, col = tid & 127;
        float gg = g2[col], bb = be2[col];
        float mx = -3.4e38f;
#pragma unroll 4
        for (int r = 0; r < K_; ++r) {
          int row = q * K_ + r;
          float v = H2[row * 132 + col];
          float o = (v - s_mu[row]) * s_rs[row] * gg + bb;
          mx = fmaxf(mx, o);
        }
        out1[(size_t)(cm0 + q) * OUT_ + col] = mx;   // FLOAT32 output
      }
      __syncthreads();
    }
  }
}

extern "C" void kernel_launch(void* const* d_in, const int* in_sizes, int n_in,
                              void* d_out, int out_size, void* d_ws, size_t ws_size,
                              hipStream_t stream) {
  const float* x = (const float*)d_in[0];
  const float* features = (const float*)d_in[1];
  const int* first_idx = (const int*)d_in[2];
  const float* w1 = (const float*)d_in[3];
  const float* b1 = (const float*)d_in[4];
  const float* g1 = (const float*)d_in[5];
  const float* be1 = (const float*)d_in[6];
  const float* w2 = (const float*)d_in[7];
  const float* b2 = (const float*)d_in[8];
  const float* g2 = (const float*)d_in[9];
  const float* be2 = (const float*)d_in[10];

  // d_out is FLOAT32: centers (8,2048,3) then out (8,2048,128), concatenated.
  float* centers = (float*)d_out;
  float* out1 = (float*)d_out + (size_t)B_ * M_ * 3;

  // ws layout (bytes): prog [0,1024) cacheline-padded (stride 32 ints/batch) |
  //                    w1p [2097152,2149376) | w2p [2149376,2223104)
  int* prog = (int*)d_ws;
  unsigned short* w1p = (unsigned short*)((char*)d_ws + 2097152);
  unsigned short* w2p = (unsigned short*)((char*)d_ws + 2149376);

  pack_kernel<<<dim3(246), dim3(256), 0, stream>>>(w1, w2, w1p, w2p, prog);
  fused_kernel<<<dim3(B_ + CONS_), dim3(512), 0, stream>>>(
      x, features, first_idx, w1p, b1, g1, be1, w2p, b2, g2, be2,
      centers, out1, prog);
}